// Round 8
// baseline (355.801 us; speedup 1.0000x reference)
//
#include <hip/hip_runtime.h>
#include <hip/hip_cooperative_groups.h>
#include <hip/hip_bf16.h>
#include <cstdint>
#include <cstddef>

namespace cg = cooperative_groups;

#define GAS __attribute__((address_space(1)))
#define LAS __attribute__((address_space(3)))

typedef __attribute__((ext_vector_type(8))) __bf16 bf16x8;
typedef __attribute__((ext_vector_type(4))) float f32x4;

constexpr int kB = 8, kS = 2048, kK = 1024, kH = 1024;
constexpr int kM = kB * kS;      // 16384 rows
constexpr int kN2 = 2 * kH;
constexpr int BM = 256, BK = 32;
constexpr int NKT = kK / BK;     // 32 K-tiles

// workspace layout (bytes)
constexpr size_t kOffXb  = 0;            // bf16 x / inp (33,554,432), in-place
constexpr size_t kOffW0  = 33554432;     // bf16 w0 (4,194,304)
constexpr size_t kOffW1  = 37748736;     // bf16 w1 (4,194,304)
constexpr size_t kOffCA  = 41943040;     // f32 chunk A (262,144)
constexpr size_t kOffCV  = 42205184;     // f32 chunk V (262,144)
constexpr size_t kWsNeed = 42467328;

__device__ __forceinline__ ushort f2bf(float f) {
    union { float f; uint32_t u; } v; v.f = f;
    uint32_t r = v.u + 0x7FFFu + ((v.u >> 16) & 1u);
    return (ushort)(r >> 16);
}
__device__ __forceinline__ float bf2f(ushort u) {
    union { uint32_t u; float f; } v; v.u = (uint32_t)u << 16;
    return v.f;
}

// ---------------- fp32 -> bf16 convert (vectorized) ----------------
__global__ void cvt_bf16_kernel(const float* __restrict__ src, ushort* __restrict__ dst, int n4) {
    int i = blockIdx.x * blockDim.x + threadIdx.x;
    if (i >= n4) return;
    f32x4 v = *reinterpret_cast<const f32x4*>(src + (size_t)i * 4);
    ushort4 o;
    o.x = f2bf(v.x); o.y = f2bf(v.y); o.z = f2bf(v.z); o.w = f2bf(v.w);
    *reinterpret_cast<ushort4*>(dst + (size_t)i * 4) = o;
}

// ---------------- one GEMM tile (validated r7 K-loop) + gating->LDS + seg sums + chunk summary
// LDS layout: ring bufs bytes 0..131071; a_lds [256][132] bf16 @0; g_lds @ushort 33792;
// sumA f32[4][128] @byte 135168; sumV @byte 137216. (a/g overlap ring -- sequential use.)
__device__ __forceinline__ void do_tile(const ushort* __restrict__ Ain,
                                        const ushort* __restrict__ Wt,
                                        const float* __restrict__ bias,
                                        ushort* smem, int m0, int j0, int tid,
                                        float* __restrict__ cA, float* __restrict__ cV,
                                        int b, int c)
{
    const int lane = tid & 63;
    const int wv   = tid >> 6;
    const int wm   = wv >> 2;
    const int wn   = wv & 3;

    __syncthreads();   // prior phase may still read a_lds/g_lds (overlaps ring)

    f32x4 acc[8][4];
#pragma unroll
    for (int i = 0; i < 8; ++i)
#pragma unroll
        for (int j = 0; j < 4; ++j) acc[i][j] = (f32x4){0.f, 0.f, 0.f, 0.f};

    const int srow  = wv * 16 + (lane >> 2);
    const int sslot = (lane & 3) ^ ((lane >> 3) & 3);
    const int scol  = sslot * 8;

    const ushort* ga0 = Ain + (size_t)(m0 + srow) * kK + scol;
    const ushort* ga1 = ga0 + (size_t)128 * kK;
    const ushort* gb0 = Wt + (size_t)(j0 + srow) * kK + scol;           // gate rows
    const ushort* gb1 = Wt + (size_t)(1024 + j0 + srow) * kK + scol;    // hidden rows

    char* lds = (char*)smem;
    const int ldsw = wv * 1024;
    const int rslot = (lane >> 4) ^ ((lane >> 1) & 3);
    const int rb    = (lane & 15) * 64 + rslot * 16;
    const int aoff  = wm * 8192 + rb;
    const int boff  = 16384 + wn * 4096 + rb;

#define VMWAIT(N) asm volatile("s_waitcnt vmcnt(" #N ")" ::: "memory")

#define STAGE_A(SBUF) do {                                                       \
    __builtin_amdgcn_global_load_lds((const GAS void*)(ga0),                     \
        (LAS void*)(lds + (SBUF) * 32768 + ldsw),          16, 0, 0);            \
    __builtin_amdgcn_global_load_lds((const GAS void*)(ga1),                     \
        (LAS void*)(lds + (SBUF) * 32768 + 8192  + ldsw),  16, 0, 0);            \
  } while (0)

#define STAGE_B(SBUF) do {                                                       \
    __builtin_amdgcn_global_load_lds((const GAS void*)(gb0),                     \
        (LAS void*)(lds + (SBUF) * 32768 + 16384 + ldsw),  16, 0, 0);            \
    __builtin_amdgcn_global_load_lds((const GAS void*)(gb1),                     \
        (LAS void*)(lds + (SBUF) * 32768 + 24576 + ldsw),  16, 0, 0);            \
    ga0 += BK; ga1 += BK; gb0 += BK; gb1 += BK;                                  \
  } while (0)

#define TILE_GEN(BUF, SA, SB, EW) do {                                           \
    bf16x8 bf_[4], af_[4];                                                       \
    _Pragma("unroll")                                                            \
    for (int nf_ = 0; nf_ < 4; ++nf_)                                            \
        bf_[nf_] = *reinterpret_cast<const bf16x8*>(                             \
            lds + (BUF) * 32768 + boff + nf_ * 1024);                            \
    _Pragma("unroll")                                                            \
    for (int mf_ = 0; mf_ < 4; ++mf_)                                            \
        af_[mf_] = *reinterpret_cast<const bf16x8*>(                             \
            lds + (BUF) * 32768 + aoff + mf_ * 1024);                            \
    SA;                                                                          \
    __builtin_amdgcn_s_barrier();                                                \
    asm volatile("s_waitcnt lgkmcnt(0)" ::: "memory");                           \
    __builtin_amdgcn_sched_barrier(0);                                           \
    __builtin_amdgcn_s_setprio(1);                                               \
    _Pragma("unroll")                                                            \
    for (int mf_ = 0; mf_ < 4; ++mf_)                                            \
        _Pragma("unroll")                                                        \
        for (int nf_ = 0; nf_ < 4; ++nf_)                                        \
            acc[mf_][nf_] = __builtin_amdgcn_mfma_f32_16x16x32_bf16(             \
                af_[mf_], bf_[nf_], acc[mf_][nf_], 0, 0, 0);                     \
    __builtin_amdgcn_s_setprio(0);                                               \
    __builtin_amdgcn_s_barrier();                                                \
    _Pragma("unroll")                                                            \
    for (int mf_ = 0; mf_ < 4; ++mf_)                                            \
        af_[mf_] = *reinterpret_cast<const bf16x8*>(                             \
            lds + (BUF) * 32768 + aoff + 4096 + mf_ * 1024);                     \
    SB;                                                                          \
    __builtin_amdgcn_s_barrier();                                                \
    asm volatile("s_waitcnt lgkmcnt(0)" ::: "memory");                           \
    __builtin_amdgcn_sched_barrier(0);                                           \
    __builtin_amdgcn_s_setprio(1);                                               \
    _Pragma("unroll")                                                            \
    for (int mf_ = 0; mf_ < 4; ++mf_)                                            \
        _Pragma("unroll")                                                        \
        for (int nf_ = 0; nf_ < 4; ++nf_)                                        \
            acc[4 + mf_][nf_] = __builtin_amdgcn_mfma_f32_16x16x32_bf16(         \
                af_[mf_], bf_[nf_], acc[4 + mf_][nf_], 0, 0, 0);                 \
    __builtin_amdgcn_s_setprio(0);                                               \
    EW;                                                                          \
    __builtin_amdgcn_s_barrier();                                                \
  } while (0)

#define TILE(BUF, SBUF) TILE_GEN(BUF, STAGE_A(SBUF), STAGE_B(SBUF), VMWAIT(4))
#define TAIL0(BUF)      TILE_GEN(BUF, (void)0, (void)0, VMWAIT(0))
#define TAIL1(BUF)      TILE_GEN(BUF, (void)0, (void)0, (void)0)

    STAGE_A(0); STAGE_B(0);
    STAGE_A(1); STAGE_B(1);
    VMWAIT(4);
    __builtin_amdgcn_s_barrier();

    for (int g = 0; g < 7; ++g) {
        TILE(0, 2);
        TILE(1, 3);
        TILE(2, 0);
        TILE(3, 1);
    }
    TILE(0, 2);
    TILE(1, 3);
    TAIL0(2);
    TAIL1(3);

#undef TILE
#undef TAIL0
#undef TAIL1
#undef TILE_GEN
#undef STAGE_A
#undef STAGE_B
#undef VMWAIT

    // gating transform -> LDS
    ushort* a_lds = smem;
    ushort* g_lds = smem + 33792;
    float*  sumA  = (float*)(smem + 67584);
    float*  sumV  = sumA + 512;
    {
        const bool isG = (wn < 2);
        ushort* tgt = isG ? a_lds : g_lds;
        const int jl = (wn & 1) * 64;
        float bn[4];
#pragma unroll
        for (int nf = 0; nf < 4; ++nf)
            bn[nf] = bias[(isG ? 0 : 1024) + j0 + jl + nf * 16 + (lane & 15)];
#pragma unroll
        for (int mf = 0; mf < 8; ++mf) {
#pragma unroll
            for (int i = 0; i < 4; ++i) {
                const int m = wm * 128 + mf * 16 + (lane >> 4) * 4 + i;
#pragma unroll
                for (int nf = 0; nf < 4; ++nf) {
                    float val = acc[mf][nf][i] + bn[nf];
                    float r;
                    if (isG) r = 1.f / (1.f + __expf(val));                 // sigmoid(-gate)
                    else     r = (val >= 0.f) ? val + 0.5f : 1.f / (1.f + __expf(-val)); // g(hidden)
                    tgt[m * 132 + jl + nf * 16 + (lane & 15)] = f2bf(r);
                }
            }
        }
    }
    __syncthreads();

    // segment sums + chunk summary (f32)
    {
        const int j  = tid & 127;
        const int sg = tid >> 7;
        float A1 = 1.f, V1 = 0.f;
#pragma unroll 4
        for (int t = 0; t < 64; ++t) {
            const int s = sg * 64 + t;
            float a = bf2f(a_lds[s * 132 + j]);
            float g = bf2f(g_lds[s * 132 + j]);
            V1 = a * V1 + (1.f - a) * g;
            A1 *= a;
        }
        sumA[sg * 128 + j] = A1;
        sumV[sg * 128 + j] = V1;
        __syncthreads();
        if (sg == 0) {
            float Ar = 1.f, Vr = 0.f;
#pragma unroll
            for (int k = 0; k < 4; ++k) {
                float Ak = sumA[k * 128 + j], Vk = sumV[k * 128 + j];
                Vr = Ak * Vr + Vk;
                Ar *= Ak;
            }
            cA[((b * 8 + c) << 10) + j0 + j] = Ar;
            cV[((b * 8 + c) << 10) + j0 + j] = Vr;
        }
    }
}

// ---------------- apply phase: h_cs from h0+summaries, f32 recurrence from LDS a,g,
// fused residual; writes inp (bf16, in-place) or final out (f32). Emits h_final at c==7.
template<bool WRITE_F32>
__device__ __forceinline__ void do_apply(ushort* smem, int m0, int j0, int tid,
    const float* __restrict__ cA, const float* __restrict__ cV,
    const float* __restrict__ h0L, const ushort* __restrict__ res,
    void* __restrict__ outp, float* __restrict__ outhL, int b, int c)
{
    ushort* a_lds = smem;
    ushort* g_lds = smem + 33792;
    float*  sumA  = (float*)(smem + 67584);
    float*  sumV  = sumA + 512;
    const int j  = tid & 127;
    const int sg = tid >> 7;

    float hv = h0L[(b << 10) + j0 + j];
    for (int k = 0; k < c; ++k) {
        int o = ((b * 8 + k) << 10) + j0 + j;
        hv = cA[o] * hv + cV[o];
    }
    for (int k = 0; k < sg; ++k)
        hv = sumA[k * 128 + j] * hv + sumV[k * 128 + j];

    const size_t gbase = (size_t)(m0 + sg * 64) * kH + j0 + j;
    const ushort* rp = res + gbase;
#pragma unroll 4
    for (int t = 0; t < 64; ++t) {
        const int s = sg * 64 + t;
        float a = bf2f(a_lds[s * 132 + j]);
        float g = bf2f(g_lds[s * 132 + j]);
        hv = a * hv + (1.f - a) * g;
        float o = hv + bf2f(*rp);
        if (WRITE_F32) ((float*)outp)[gbase + (size_t)t * kH] = o;
        else           ((ushort*)outp)[gbase + (size_t)t * kH] = f2bf(o);
        rp += kH;
    }
    if (c == 7 && sg == 3) outhL[(b << 10) + j0 + j] = hv;
}

// ---------------- the whole net: 2 layers, 4 grid syncs ----------------
__global__ __launch_bounds__(512, 1)
void fused_mingru_kernel(ushort* xb,            // x bf16, becomes inp in-place
                         const ushort* w0b, const ushort* w1b,
                         const float* b0, const float* b1,
                         const float* h0,
                         float* cA, float* cV,
                         float* out)
{
    __shared__ ushort smem[69632];
    cg::grid_group grid = cg::this_grid();

    const int tid = threadIdx.x;
    const int k   = blockIdx.x;        // 0..255
    const int j0  = (k & 7) * 128;
    const int tmA = k >> 3;            // batches 0..3
    const int tmB = 32 + (k >> 3);     // batches 4..7

    float* out_h = out + (size_t)kM * kH;
    const float* h1 = h0 + 8192;

    // ---- layer 0 (reads xb=x, writes inp in-place) ----
    do_tile(xb, w0b, b0, smem, tmA * BM, j0, tid, cA, cV, tmA >> 3, tmA & 7);
    grid.sync();
    do_apply<false>(smem, tmA * BM, j0, tid, cA, cV, h0, xb, (void*)xb, out_h, tmA >> 3, tmA & 7);
    do_tile(xb, w0b, b0, smem, tmB * BM, j0, tid, cA, cV, tmB >> 3, tmB & 7);   // rows b4-7: still original x
    grid.sync();
    do_apply<false>(smem, tmB * BM, j0, tid, cA, cV, h0, xb, (void*)xb, out_h, tmB >> 3, tmB & 7);

    // ---- layer 1 (reads inp rows b0-3, which are final since sync #1) ----
    do_tile(xb, w1b, b1, smem, tmA * BM, j0, tid, cA, cV, tmA >> 3, tmA & 7);
    grid.sync();   // also publishes Ap-B's inp rows b4-7 for G-B below
    do_apply<true>(smem, tmA * BM, j0, tid, cA, cV, h1, xb, (void*)out, out_h + 8192, tmA >> 3, tmA & 7);
    do_tile(xb, w1b, b1, smem, tmB * BM, j0, tid, cA, cV, tmB >> 3, tmB & 7);
    grid.sync();
    do_apply<true>(smem, tmB * BM, j0, tid, cA, cV, h1, xb, (void*)out, out_h + 8192, tmB >> 3, tmB & 7);
}

extern "C" void kernel_launch(void* const* d_in, const int* in_sizes, int n_in,
                              void* d_out, int out_size, void* d_ws, size_t ws_size,
                              hipStream_t stream)
{
    const float* x  = (const float*)d_in[0];
    const float* h  = (const float*)d_in[1];   // (2, 8, 1, 1024)
    const float* w0 = (const float*)d_in[2];
    const float* b0 = (const float*)d_in[3];
    const float* w1 = (const float*)d_in[4];
    const float* b1 = (const float*)d_in[5];
    float* out = (float*)d_out;
    char* ws = (char*)d_ws;

    if (ws_size < kWsNeed) return;

    ushort* xb  = (ushort*)(ws + kOffXb);
    ushort* w0b = (ushort*)(ws + kOffW0);
    ushort* w1b = (ushort*)(ws + kOffW1);
    float*  cA  = (float*)(ws + kOffCA);
    float*  cV  = (float*)(ws + kOffCV);

    cvt_bf16_kernel<<<(kM * kK / 4 + 255) / 256, 256, 0, stream>>>(x, xb, kM * kK / 4);
    cvt_bf16_kernel<<<(kN2 * kK / 4 + 255) / 256, 256, 0, stream>>>(w0, w0b, kN2 * kK / 4);
    cvt_bf16_kernel<<<(kN2 * kK / 4 + 255) / 256, 256, 0, stream>>>(w1, w1b, kN2 * kK / 4);

    const ushort* w0bc = w0b; const ushort* w1bc = w1b;
    const float*  b0c = b0;  const float*  b1c = b1;  const float* hc = h;
    void* args[] = { (void*)&xb, (void*)&w0bc, (void*)&w1bc, (void*)&b0c, (void*)&b1c,
                     (void*)&hc, (void*)&cA, (void*)&cV, (void*)&out };
    hipLaunchCooperativeKernel((const void*)fused_mingru_kernel,
                               dim3(256), dim3(512), args, 0, stream);
}

// Round 9
// 270.885 us; speedup vs baseline: 1.3135x; 1.3135x over previous
//
#include <hip/hip_runtime.h>
#include <hip/hip_bf16.h>
#include <cstdint>
#include <cstddef>

#define GAS __attribute__((address_space(1)))
#define LAS __attribute__((address_space(3)))

typedef __attribute__((ext_vector_type(8))) __bf16 bf16x8;
typedef __attribute__((ext_vector_type(4))) float f32x4;

constexpr int kB = 8, kS = 2048, kK = 1024, kH = 1024;
constexpr int kM = kB * kS;      // 16384 rows
constexpr int kN2 = 2 * kH;      // 2048 output cols of the GEMM
constexpr int BM = 256, BK = 32;
constexpr int NKT = kK / BK;     // 32 K-tiles

// workspace layout (bytes)
constexpr size_t kOffXb   = 0;                    // bf16 x  (33,554,432) -- later reused as inpb
constexpr size_t kOffW0   = 33554432;             // bf16 w0 ( 4,194,304)
constexpr size_t kOffW1   = 37748736;             // bf16 w1 ( 4,194,304)
constexpr size_t kOffA    = 41943040;             // bf16 A_pref (33,554,432)
constexpr size_t kOffG    = 75497472;             // bf16 V_pref (33,554,432)
constexpr size_t kOffCA   = 109051904;            // f32 chunk A (262,144)
constexpr size_t kOffCV   = 111149056;            // f32 chunk V (262,144)
constexpr size_t kOffHst  = 113246208;            // f32 chunk h-start (262,144)
constexpr size_t kWsNeed  = 115343360;

__device__ __forceinline__ ushort f2bf(float f) {
    union { float f; uint32_t u; } v; v.f = f;
    uint32_t r = v.u + 0x7FFFu + ((v.u >> 16) & 1u);
    return (ushort)(r >> 16);
}
__device__ __forceinline__ float bf2f(ushort u) {
    union { uint32_t u; float f; } v; v.u = (uint32_t)u << 16;
    return v.f;
}

// ---------------- fp32 -> bf16 convert: x, w0, w1 in ONE launch ----------------
constexpr int QX = kM * kK / 4;      // 4,194,304 quads
constexpr int QW = kN2 * kK / 4;     //   524,288 quads
__global__ void cvt3_kernel(const float* __restrict__ x, const float* __restrict__ w0,
                            const float* __restrict__ w1,
                            ushort* __restrict__ xb, ushort* __restrict__ w0b,
                            ushort* __restrict__ w1b)
{
    int i = blockIdx.x * 256 + threadIdx.x;        // 0 .. QX+2*QW-1
    const float* s; ushort* d;
    if (i < QX)            { s = x  + (size_t)i * 4;            d = xb  + (size_t)i * 4; }
    else if (i < QX + QW)  { int k = i - QX;      s = w0 + (size_t)k * 4; d = w0b + (size_t)k * 4; }
    else                   { int k = i - QX - QW; s = w1 + (size_t)k * 4; d = w1b + (size_t)k * 4; }
    f32x4 v = *reinterpret_cast<const f32x4*>(s);
    ushort4 o;
    o.x = f2bf(v.x); o.y = f2bf(v.y); o.z = f2bf(v.z); o.w = f2bf(v.w);
    *reinterpret_cast<ushort4*>(d) = o;
}

// ---------------- GEMM + gating + fused block-local scan (validated round-7) ----------------
// Per block: 256 m-rows (one b, 256 contiguous s-steps = one chunk) x 128 j-columns,
// computing BOTH gate (W rows j0..j0+127) and hidden (W rows 1024+j0..) for those j.
// K-loop: 4-deep LDS ring, counted vmcnt(4), 2 phases/K-tile, T2 swizzle.
// Epilogue: a=sigmoid(-gate), g(hidden) -> LDS; 128j x 4seg threads run f32 prefix scan
// over the 256 steps; store per-element A_pref/V_pref (bf16) + chunk summary (f32).
__global__ __launch_bounds__(512, 1)
void gemm_scan_kernel(const ushort* __restrict__ A, const ushort* __restrict__ W,
                      const float* __restrict__ bias,
                      ushort* __restrict__ Apref, ushort* __restrict__ Vpref,
                      float* __restrict__ cA, float* __restrict__ cV)
{
    __shared__ ushort smem[69632];

    const int tid  = threadIdx.x;
    const int lane = tid & 63;
    const int wv   = tid >> 6;     // 0..7
    const int wm   = wv >> 2;      // 0..1 : row half
    const int wn   = wv & 3;       // 0..3 : col quarter

    // XCD-bijective swizzle: 512 blocks, 8 XCDs
    const int bid = blockIdx.x;
    const int sid = (bid & 7) * 64 + (bid >> 3);
    const int tm  = sid >> 3;      // 0..63
    const int tn  = sid & 7;       // 0..7
    const int m0  = tm * BM;
    const int j0  = tn * 128;      // this block's 128 j-columns

    f32x4 acc[8][4];
#pragma unroll
    for (int i = 0; i < 8; ++i)
#pragma unroll
        for (int j = 0; j < 4; ++j) acc[i][j] = (f32x4){0.f, 0.f, 0.f, 0.f};

    const int srow  = wv * 16 + (lane >> 2);
    const int sslot = (lane & 3) ^ ((lane >> 3) & 3);
    const int scol  = sslot * 8;   // elems

    const ushort* ga0 = A + (size_t)(m0 + srow) * kK + scol;            // A rows   0..127
    const ushort* ga1 = ga0 + (size_t)128 * kK;                         // A rows 128..255
    const ushort* gb0 = W + (size_t)(j0 + srow) * kK + scol;            // gate rows
    const ushort* gb1 = W + (size_t)(1024 + j0 + srow) * kK + scol;     // hidden rows

    char* lds = (char*)smem;
    const int ldsw = wv * 1024;

    const int rslot = (lane >> 4) ^ ((lane >> 1) & 3);
    const int rb    = (lane & 15) * 64 + rslot * 16;
    const int aoff  = wm * 8192 + rb;
    const int boff  = 16384 + wn * 4096 + rb;

#define VMWAIT(N) asm volatile("s_waitcnt vmcnt(" #N ")" ::: "memory")

#define STAGE_A(SBUF) do {                                                       \
    __builtin_amdgcn_global_load_lds((const GAS void*)(ga0),                     \
        (LAS void*)(lds + (SBUF) * 32768 + ldsw),          16, 0, 0);            \
    __builtin_amdgcn_global_load_lds((const GAS void*)(ga1),                     \
        (LAS void*)(lds + (SBUF) * 32768 + 8192  + ldsw),  16, 0, 0);            \
  } while (0)

#define STAGE_B(SBUF) do {                                                       \
    __builtin_amdgcn_global_load_lds((const GAS void*)(gb0),                     \
        (LAS void*)(lds + (SBUF) * 32768 + 16384 + ldsw),  16, 0, 0);            \
    __builtin_amdgcn_global_load_lds((const GAS void*)(gb1),                     \
        (LAS void*)(lds + (SBUF) * 32768 + 24576 + ldsw),  16, 0, 0);            \
    ga0 += BK; ga1 += BK; gb0 += BK; gb1 += BK;                                  \
  } while (0)

#define TILE_GEN(BUF, SA, SB, EW) do {                                           \
    bf16x8 bf_[4], af_[4];                                                       \
    _Pragma("unroll")                                                            \
    for (int nf_ = 0; nf_ < 4; ++nf_)                                            \
        bf_[nf_] = *reinterpret_cast<const bf16x8*>(                             \
            lds + (BUF) * 32768 + boff + nf_ * 1024);                            \
    _Pragma("unroll")                                                            \
    for (int mf_ = 0; mf_ < 4; ++mf_)                                            \
        af_[mf_] = *reinterpret_cast<const bf16x8*>(                             \
            lds + (BUF) * 32768 + aoff + mf_ * 1024);                            \
    SA;                                                                          \
    __builtin_amdgcn_s_barrier();                                                \
    asm volatile("s_waitcnt lgkmcnt(0)" ::: "memory");                           \
    __builtin_amdgcn_sched_barrier(0);                                           \
    __builtin_amdgcn_s_setprio(1);                                               \
    _Pragma("unroll")                                                            \
    for (int mf_ = 0; mf_ < 4; ++mf_)                                            \
        _Pragma("unroll")                                                        \
        for (int nf_ = 0; nf_ < 4; ++nf_)                                        \
            acc[mf_][nf_] = __builtin_amdgcn_mfma_f32_16x16x32_bf16(             \
                af_[mf_], bf_[nf_], acc[mf_][nf_], 0, 0, 0);                     \
    __builtin_amdgcn_s_setprio(0);                                               \
    __builtin_amdgcn_s_barrier();                                                \
    _Pragma("unroll")                                                            \
    for (int mf_ = 0; mf_ < 4; ++mf_)                                            \
        af_[mf_] = *reinterpret_cast<const bf16x8*>(                             \
            lds + (BUF) * 32768 + aoff + 4096 + mf_ * 1024);                     \
    SB;                                                                          \
    __builtin_amdgcn_s_barrier();                                                \
    asm volatile("s_waitcnt lgkmcnt(0)" ::: "memory");                           \
    __builtin_amdgcn_sched_barrier(0);                                           \
    __builtin_amdgcn_s_setprio(1);                                               \
    _Pragma("unroll")                                                            \
    for (int mf_ = 0; mf_ < 4; ++mf_)                                            \
        _Pragma("unroll")                                                        \
        for (int nf_ = 0; nf_ < 4; ++nf_)                                        \
            acc[4 + mf_][nf_] = __builtin_amdgcn_mfma_f32_16x16x32_bf16(         \
                af_[mf_], bf_[nf_], acc[4 + mf_][nf_], 0, 0, 0);                 \
    __builtin_amdgcn_s_setprio(0);                                               \
    EW;                                                                          \
    __builtin_amdgcn_s_barrier();                                                \
  } while (0)

#define TILE(BUF, SBUF) TILE_GEN(BUF, STAGE_A(SBUF), STAGE_B(SBUF), VMWAIT(4))
#define TAIL0(BUF)      TILE_GEN(BUF, (void)0, (void)0, VMWAIT(0))
#define TAIL1(BUF)      TILE_GEN(BUF, (void)0, (void)0, (void)0)

    STAGE_A(0); STAGE_B(0);
    STAGE_A(1); STAGE_B(1);
    VMWAIT(4);
    __builtin_amdgcn_s_barrier();

    for (int g = 0; g < 7; ++g) {
        TILE(0, 2);
        TILE(1, 3);
        TILE(2, 0);
        TILE(3, 1);
    }
    TILE(0, 2);
    TILE(1, 3);
    TAIL0(2);
    TAIL1(3);

#undef TILE
#undef TAIL0
#undef TAIL1
#undef TILE_GEN
#undef STAGE_A
#undef STAGE_B
#undef VMWAIT

    // ---- Epilogue part 1: gating transform -> LDS ----
    ushort* a_lds = smem;                      // [256][132] bf16
    ushort* g_lds = smem + 33792;              // [256][132] bf16
    float*  sumA  = (float*)(smem + 67584);    // [4][128]
    float*  sumV  = sumA + 512;

    {
        const bool isG = (wn < 2);
        ushort* tgt = isG ? a_lds : g_lds;
        const int jl = (wn & 1) * 64;
        float bn[4];
#pragma unroll
        for (int nf = 0; nf < 4; ++nf)
            bn[nf] = bias[(isG ? 0 : 1024) + j0 + jl + nf * 16 + (lane & 15)];
#pragma unroll
        for (int mf = 0; mf < 8; ++mf) {
#pragma unroll
            for (int i = 0; i < 4; ++i) {
                const int m = wm * 128 + mf * 16 + (lane >> 4) * 4 + i;  // 0..255 local s
#pragma unroll
                for (int nf = 0; nf < 4; ++nf) {
                    float val = acc[mf][nf][i] + bn[nf];
                    float r;
                    if (isG) r = 1.f / (1.f + __expf(val));                 // sigmoid(-gate)
                    else     r = (val >= 0.f) ? val + 0.5f : 1.f / (1.f + __expf(-val)); // g(hidden)
                    tgt[m * 132 + jl + nf * 16 + (lane & 15)] = f2bf(r);
                }
            }
        }
    }
    __syncthreads();

    // ---- Epilogue part 2: block-local prefix scan (f32), store prefixes + summary ----
    {
        const int j  = tid & 127;     // local j
        const int sg = tid >> 7;      // segment 0..3 (64 steps each)
        float A1 = 1.f, V1 = 0.f;
#pragma unroll 4
        for (int t = 0; t < 64; ++t) {
            const int s = sg * 64 + t;
            float a = bf2f(a_lds[s * 132 + j]);
            float g = bf2f(g_lds[s * 132 + j]);
            V1 = a * V1 + (1.f - a) * g;
            A1 *= a;
        }
        sumA[sg * 128 + j] = A1;
        sumV[sg * 128 + j] = V1;
        __syncthreads();
        float Ar = 1.f, Vr = 0.f;
        for (int k = 0; k < sg; ++k) {
            float Ak = sumA[k * 128 + j], Vk = sumV[k * 128 + j];
            Vr = Ak * Vr + Vk;
            Ar *= Ak;
        }
        ushort* ApG = Apref + (size_t)(m0 + sg * 64) * kH + j0 + j;
        ushort* VpG = Vpref + (size_t)(m0 + sg * 64) * kH + j0 + j;
#pragma unroll 4
        for (int t = 0; t < 64; ++t) {
            const int s = sg * 64 + t;
            float a = bf2f(a_lds[s * 132 + j]);
            float g = bf2f(g_lds[s * 132 + j]);
            Vr = a * Vr + (1.f - a) * g;
            Ar *= a;
            *ApG = f2bf(Ar);
            *VpG = f2bf(Vr);
            ApG += kH; VpG += kH;
        }
        if (sg == 3) {
            const int b = tm >> 3, c = tm & 7;      // chunk = 256 steps = this block
            cA[((b * 8 + c) << 10) + j0 + j] = Ar;  // f32 summary
            cV[((b * 8 + c) << 10) + j0 + j] = Vr;
        }
    }
}

// ---------------- mid-scan over 8 chunks/b; emits h_chunkstart + h_final ----------------
__global__ void scan_chunks_kernel(const float* __restrict__ cA, const float* __restrict__ cV,
                                   const float* __restrict__ h0, float* __restrict__ hstart,
                                   float* __restrict__ hfin)
{
    int idx = blockIdx.x * 256 + threadIdx.x;     // 8192 threads: (b, j)
    int j = idx & 1023, b = idx >> 10;
    float h = h0[(b << 10) + j];
    for (int c = 0; c < 8; ++c) {
        int o = ((b * 8 + c) << 10) + j;
        hstart[o] = h;
        h = cA[o] * h + cV[o];
    }
    hfin[(b << 10) + j] = h;
}

// ---------------- apply: elementwise out = A_pref*h_cs + V_pref + residual ----------------
template<bool WRITE_F32>
__global__ void apply_kernel(const ushort* __restrict__ Ap, const ushort* __restrict__ Vp,
                             const float* __restrict__ hst, const ushort* __restrict__ res,
                             void* __restrict__ outp)
{
    size_t i = ((size_t)blockIdx.x * 256 + threadIdx.x) * 4;
    int m = (int)(i >> 10);          // row
    int j = (int)(i & 1023);
    int b = m >> 11, s = m & 2047, c = s >> 8;
    f32x4 hcs = *reinterpret_cast<const f32x4*>(hst + (((b * 8 + c) << 10) + j));
    ushort4 Au = *reinterpret_cast<const ushort4*>(Ap + i);
    ushort4 Vu = *reinterpret_cast<const ushort4*>(Vp + i);
    ushort4 Ru = *reinterpret_cast<const ushort4*>(res + i);
    f32x4 o;
    o.x = bf2f(Au.x) * hcs.x + bf2f(Vu.x) + bf2f(Ru.x);
    o.y = bf2f(Au.y) * hcs.y + bf2f(Vu.y) + bf2f(Ru.y);
    o.z = bf2f(Au.z) * hcs.z + bf2f(Vu.z) + bf2f(Ru.z);
    o.w = bf2f(Au.w) * hcs.w + bf2f(Vu.w) + bf2f(Ru.w);
    if (WRITE_F32) {
        *reinterpret_cast<f32x4*>((float*)outp + i) = o;
    } else {
        ushort4 ob;
        ob.x = f2bf(o.x); ob.y = f2bf(o.y); ob.z = f2bf(o.z); ob.w = f2bf(o.w);
        *reinterpret_cast<ushort4*>((ushort*)outp + i) = ob;
    }
}

extern "C" void kernel_launch(void* const* d_in, const int* in_sizes, int n_in,
                              void* d_out, int out_size, void* d_ws, size_t ws_size,
                              hipStream_t stream)
{
    const float* x  = (const float*)d_in[0];
    const float* h  = (const float*)d_in[1];   // (2, 8, 1, 1024)
    const float* w0 = (const float*)d_in[2];
    const float* b0 = (const float*)d_in[3];
    const float* w1 = (const float*)d_in[4];
    const float* b1 = (const float*)d_in[5];
    float* out = (float*)d_out;
    char* ws = (char*)d_ws;

    if (ws_size < kWsNeed) return;

    ushort* xb   = (ushort*)(ws + kOffXb);   // aliases inpb (apply-L0 overwrites in place)
    ushort* inpb = (ushort*)(ws + kOffXb);
    ushort* w0b  = (ushort*)(ws + kOffW0);
    ushort* w1b  = (ushort*)(ws + kOffW1);
    ushort* Ap   = (ushort*)(ws + kOffA);
    ushort* Vp   = (ushort*)(ws + kOffG);
    float*  cA   = (float*)(ws + kOffCA);
    float*  cV   = (float*)(ws + kOffCV);
    float*  hst  = (float*)(ws + kOffHst);

    float* out_h = out + (size_t)kM * kH;    // h_final region in d_out

    cvt3_kernel<<<(QX + 2 * QW) / 256, 256, 0, stream>>>(x, w0, w1, xb, w0b, w1b);

    const int gemm_grid  = (kM / BM) * (kN2 / 256);  // 512
    const int apply_grid = kM * kH / 4 / 256;        // 16384

    // ---- layer 0 ----
    gemm_scan_kernel<<<gemm_grid, 512, 0, stream>>>(xb, w0b, b0, Ap, Vp, cA, cV);
    scan_chunks_kernel<<<32, 256, 0, stream>>>(cA, cV, h, hst, out_h);
    apply_kernel<false><<<apply_grid, 256, 0, stream>>>(Ap, Vp, hst, xb, inpb);

    // ---- layer 1 ----
    gemm_scan_kernel<<<gemm_grid, 512, 0, stream>>>(inpb, w1b, b1, Ap, Vp, cA, cV);
    scan_chunks_kernel<<<32, 256, 0, stream>>>(cA, cV, h + (size_t)kB * kH, hst, out_h + (size_t)kB * kH);
    apply_kernel<true><<<apply_grid, 256, 0, stream>>>(Ap, Vp, hst, inpb, out);
}

// Round 10
// 270.333 us; speedup vs baseline: 1.3162x; 1.0020x over previous
//
#include <hip/hip_runtime.h>
#include <hip/hip_bf16.h>
#include <cstdint>
#include <cstddef>

#define GAS __attribute__((address_space(1)))
#define LAS __attribute__((address_space(3)))

typedef __attribute__((ext_vector_type(8))) __bf16 bf16x8;
typedef __attribute__((ext_vector_type(4))) float f32x4;

constexpr int kB = 8, kS = 2048, kK = 1024, kH = 1024;
constexpr int kM = kB * kS;      // 16384 rows
constexpr int kN2 = 2 * kH;      // 2048 output cols of the GEMM
constexpr int BM = 256, BK = 64;
constexpr int NKT = kK / BK;     // 16 K-tiles

// workspace layout (bytes)
constexpr size_t kOffXb   = 0;                    // bf16 x  (33,554,432) -- later reused as inpb
constexpr size_t kOffW0   = 33554432;             // bf16 w0 ( 4,194,304)
constexpr size_t kOffW1   = 37748736;             // bf16 w1 ( 4,194,304)
constexpr size_t kOffA    = 41943040;             // bf16 A_pref (33,554,432)
constexpr size_t kOffG    = 75497472;             // bf16 V_pref (33,554,432)
constexpr size_t kOffCA   = 109051904;            // f32 chunk A (262,144)
constexpr size_t kOffCV   = 111149056;            // f32 chunk V (262,144)
constexpr size_t kOffHst  = 113246208;            // f32 chunk h-start (262,144)
constexpr size_t kWsNeed  = 115343360;

__device__ __forceinline__ ushort f2bf(float f) {
    union { float f; uint32_t u; } v; v.f = f;
    uint32_t r = v.u + 0x7FFFu + ((v.u >> 16) & 1u);
    return (ushort)(r >> 16);
}
__device__ __forceinline__ float bf2f(ushort u) {
    union { uint32_t u; float f; } v; v.u = (uint32_t)u << 16;
    return v.f;
}

// ---------------- fp32 -> bf16 convert: x, w0, w1 in ONE launch ----------------
constexpr int QX = kM * kK / 4;      // 4,194,304 quads
constexpr int QW = kN2 * kK / 4;     //   524,288 quads
__global__ void cvt3_kernel(const float* __restrict__ x, const float* __restrict__ w0,
                            const float* __restrict__ w1,
                            ushort* __restrict__ xb, ushort* __restrict__ w0b,
                            ushort* __restrict__ w1b)
{
    int i = blockIdx.x * 256 + threadIdx.x;        // 0 .. QX+2*QW-1
    const float* s; ushort* d;
    if (i < QX)            { s = x  + (size_t)i * 4;            d = xb  + (size_t)i * 4; }
    else if (i < QX + QW)  { int k = i - QX;      s = w0 + (size_t)k * 4; d = w0b + (size_t)k * 4; }
    else                   { int k = i - QX - QW; s = w1 + (size_t)k * 4; d = w1b + (size_t)k * 4; }
    f32x4 v = *reinterpret_cast<const f32x4*>(s);
    ushort4 o;
    o.x = f2bf(v.x); o.y = f2bf(v.y); o.z = f2bf(v.z); o.w = f2bf(v.w);
    *reinterpret_cast<ushort4*>(d) = o;
}

// ---------------- GEMM + gating + fused block-local scan ----------------
// 8-phase-style K-loop (m201 port): BK=64, 2-deep LDS ring (2 x 64KB), 4 phases per
// K-tile, each phase = {stage 1 half-tile (2 gload_lds) || ds_read subtile -> barrier ->
// lgkmcnt(0) -> setprio 16 MFMA -> barrier}; counted vmcnt(4) at end of P1 and P3 only.
// Each 16KB k-half block keeps the r6-validated [256][32] layout + 0-conflict XOR swizzle
// (pre-swizzled global source, swizzled ds_read slot).
// Epilogue (validated r7): a=sigmoid(-gate), g(hidden) -> LDS; f32 prefix scan over the
// 256 steps; store per-element A_pref/V_pref (bf16) + chunk summary (f32).
__global__ __launch_bounds__(512, 1)
void gemm_scan_kernel(const ushort* __restrict__ A, const ushort* __restrict__ W,
                      const float* __restrict__ bias,
                      ushort* __restrict__ Apref, ushort* __restrict__ Vpref,
                      float* __restrict__ cA, float* __restrict__ cV)
{
    // ring: 2 bufs x { A: [kh0 16KB][kh1 16KB], B: [kh0 16KB][kh1 16KB] } = 131072 B
    // epilogue overlay: a_lds/g_lds [256][132] bf16 + sums = 139264 B
    __shared__ ushort smem[69632];

    const int tid  = threadIdx.x;
    const int lane = tid & 63;
    const int wv   = tid >> 6;     // 0..7
    const int wm   = wv >> 2;      // 0..1 : row half
    const int wn   = wv & 3;       // 0..3 : col quarter

    // XCD-bijective swizzle: 512 blocks, 8 XCDs
    const int bid = blockIdx.x;
    const int sid = (bid & 7) * 64 + (bid >> 3);
    const int tm  = sid >> 3;      // 0..63
    const int tn  = sid & 7;       // 0..7
    const int m0  = tm * BM;
    const int j0  = tn * 128;      // this block's 128 j-columns

    f32x4 acc[8][4];
#pragma unroll
    for (int i = 0; i < 8; ++i)
#pragma unroll
        for (int j = 0; j < 4; ++j) acc[i][j] = (f32x4){0.f, 0.f, 0.f, 0.f};

    // staging: lane l -> row (l>>2), linear dest slot (l&3); pre-swizzled source k-slot
    const int srow  = wv * 16 + (lane >> 2);
    const int sslot = (lane & 3) ^ ((lane >> 3) & 3);
    const int scol  = sslot * 8;   // elems within a 32-elem k-half

    const ushort* ga0 = A + (size_t)(m0 + srow) * kK + scol;            // A rows   0..127
    const ushort* ga1 = ga0 + (size_t)128 * kK;                         // A rows 128..255
    const ushort* gb0 = W + (size_t)(j0 + srow) * kK + scol;            // gate rows
    const ushort* gb1 = W + (size_t)(1024 + j0 + srow) * kK + scol;     // hidden rows

    char* lds = (char*)smem;
    const int ldsw = wv * 1024;

    // read swizzle (0-conflict, r6-validated): slot = (lane>>4) ^ ((row>>1)&3)
    const int rslot = (lane >> 4) ^ ((lane >> 1) & 3);
    const int rb    = (lane & 15) * 64 + rslot * 16;
    const int aoff  = wm * 8192 + rb;            // within A k-half block
    const int boff  = 32768 + wn * 4096 + rb;    // within buf (B base), + kh*16384

#define VMWAIT(N) asm volatile("s_waitcnt vmcnt(" #N ")" ::: "memory")

#define STG_A(SBUF, KH) do {                                                     \
    __builtin_amdgcn_global_load_lds((const GAS void*)(ga0 + (KH) * 32),         \
        (LAS void*)(lds + (SBUF) * 65536 + (KH) * 16384 + ldsw),        16, 0, 0); \
    __builtin_amdgcn_global_load_lds((const GAS void*)(ga1 + (KH) * 32),         \
        (LAS void*)(lds + (SBUF) * 65536 + (KH) * 16384 + 8192 + ldsw), 16, 0, 0); \
  } while (0)

#define STG_B(SBUF, KH) do {                                                     \
    __builtin_amdgcn_global_load_lds((const GAS void*)(gb0 + (KH) * 32),         \
        (LAS void*)(lds + (SBUF) * 65536 + 32768 + (KH) * 16384 + ldsw), 16, 0, 0); \
    __builtin_amdgcn_global_load_lds((const GAS void*)(gb1 + (KH) * 32),         \
        (LAS void*)(lds + (SBUF) * 65536 + 32768 + (KH) * 16384 + 8192 + ldsw), 16, 0, 0); \
  } while (0)

#define PH_SYNC                                                                  \
    __builtin_amdgcn_s_barrier();                                                \
    asm volatile("s_waitcnt lgkmcnt(0)" ::: "memory");                           \
    __builtin_amdgcn_sched_barrier(0)

#define MFMA16(BASE)                                                             \
    __builtin_amdgcn_s_setprio(1);                                               \
    _Pragma("unroll")                                                            \
    for (int mf_ = 0; mf_ < 4; ++mf_)                                            \
        _Pragma("unroll")                                                        \
        for (int nf_ = 0; nf_ < 4; ++nf_)                                        \
            acc[(BASE) + mf_][nf_] = __builtin_amdgcn_mfma_f32_16x16x32_bf16(    \
                af_[mf_], bf_[nf_], acc[(BASE) + mf_][nf_], 0, 0, 0);            \
    __builtin_amdgcn_s_setprio(0)

// One BK=64 tile = 4 phases. S0..S3: per-phase stage statements; EW1/EW3 end-waits.
#define TILE64(BUF, S0, S1, S2, S3, EW1, EW3) do {                               \
    bf16x8 bf_[4], af_[4];                                                       \
    /* P0: kh0, mf0-3 (reads A-kh0 + B-kh0 of this tile) */                      \
    _Pragma("unroll")                                                            \
    for (int nf_ = 0; nf_ < 4; ++nf_)                                            \
        bf_[nf_] = *reinterpret_cast<const bf16x8*>(                             \
            lds + (BUF) * 65536 + boff + nf_ * 1024);                            \
    _Pragma("unroll")                                                            \
    for (int mf_ = 0; mf_ < 4; ++mf_)                                            \
        af_[mf_] = *reinterpret_cast<const bf16x8*>(                             \
            lds + (BUF) * 65536 + aoff + mf_ * 1024);                            \
    S0;                                                                          \
    PH_SYNC;                                                                     \
    MFMA16(0);                                                                   \
    __builtin_amdgcn_s_barrier();                                                \
    /* P1: kh0, mf4-7 (bf_ reused) */                                            \
    _Pragma("unroll")                                                            \
    for (int mf_ = 0; mf_ < 4; ++mf_)                                            \
        af_[mf_] = *reinterpret_cast<const bf16x8*>(                             \
            lds + (BUF) * 65536 + aoff + 4096 + mf_ * 1024);                     \
    S1;                                                                          \
    PH_SYNC;                                                                     \
    MFMA16(4);                                                                   \
    EW1;                                                                         \
    __builtin_amdgcn_s_barrier();                                                \
    /* P2: kh1, mf0-3 */                                                         \
    _Pragma("unroll")                                                            \
    for (int nf_ = 0; nf_ < 4; ++nf_)                                            \
        bf_[nf_] = *reinterpret_cast<const bf16x8*>(                             \
            lds + (BUF) * 65536 + 16384 + boff + nf_ * 1024);                    \
    _Pragma("unroll")                                                            \
    for (int mf_ = 0; mf_ < 4; ++mf_)                                            \
        af_[mf_] = *reinterpret_cast<const bf16x8*>(                             \
            lds + (BUF) * 65536 + 16384 + aoff + mf_ * 1024);                    \
    S2;                                                                          \
    PH_SYNC;                                                                     \
    MFMA16(0);                                                                   \
    __builtin_amdgcn_s_barrier();                                                \
    /* P3: kh1, mf4-7 */                                                         \
    _Pragma("unroll")                                                            \
    for (int mf_ = 0; mf_ < 4; ++mf_)                                            \
        af_[mf_] = *reinterpret_cast<const bf16x8*>(                             \
            lds + (BUF) * 65536 + 16384 + aoff + 4096 + mf_ * 1024);             \
    S3;                                                                          \
    PH_SYNC;                                                                     \
    MFMA16(4);                                                                   \
    EW3;                                                                         \
    __builtin_amdgcn_s_barrier();                                                \
  } while (0)

#define ADV do { ga0 += BK; ga1 += BK; gb0 += BK; gb1 += BK; } while (0)
#define TILE(BUF) TILE64(BUF,                                                    \
    STG_A((BUF) ^ 1, 0), STG_B((BUF) ^ 1, 0),                                    \
    STG_A((BUF) ^ 1, 1), do { STG_B((BUF) ^ 1, 1); ADV; } while (0),             \
    VMWAIT(4), VMWAIT(4))
#define TAIL(BUF) TILE64(BUF, (void)0, (void)0, (void)0, (void)0, VMWAIT(0), (void)0)

    // prologue: stage tile 0 (A-kh0, B-kh0, A-kh1, B-kh1); retire kh0 halves
    STG_A(0, 0); STG_B(0, 0); STG_A(0, 1); STG_B(0, 1);
    ADV;
    VMWAIT(4);
    __builtin_amdgcn_s_barrier();

    for (int g = 0; g < 7; ++g) {
        TILE(0);    // tile 2g,   stages tile 2g+1 -> buf1
        TILE(1);    // tile 2g+1, stages tile 2g+2 -> buf0
    }
    TILE(0);        // tile 14, stages tile 15 -> buf1
    TAIL(1);        // tile 15 (vmcnt(0) at end-P1 retires its kh1 halves)

#undef TILE
#undef TAIL
#undef TILE64
#undef MFMA16
#undef PH_SYNC
#undef STG_A
#undef STG_B
#undef ADV
#undef VMWAIT

    // ---- Epilogue part 1: gating transform -> LDS ----
    ushort* a_lds = smem;                      // [256][132] bf16
    ushort* g_lds = smem + 33792;              // [256][132] bf16
    float*  sumA  = (float*)(smem + 67584);    // [4][128]
    float*  sumV  = sumA + 512;

    {
        const bool isG = (wn < 2);
        ushort* tgt = isG ? a_lds : g_lds;
        const int jl = (wn & 1) * 64;
        float bn[4];
#pragma unroll
        for (int nf = 0; nf < 4; ++nf)
            bn[nf] = bias[(isG ? 0 : 1024) + j0 + jl + nf * 16 + (lane & 15)];
#pragma unroll
        for (int mf = 0; mf < 8; ++mf) {
#pragma unroll
            for (int i = 0; i < 4; ++i) {
                const int m = wm * 128 + mf * 16 + (lane >> 4) * 4 + i;  // 0..255 local s
#pragma unroll
                for (int nf = 0; nf < 4; ++nf) {
                    float val = acc[mf][nf][i] + bn[nf];
                    float r;
                    if (isG) r = 1.f / (1.f + __expf(val));                 // sigmoid(-gate)
                    else     r = (val >= 0.f) ? val + 0.5f : 1.f / (1.f + __expf(-val)); // g(hidden)
                    tgt[m * 132 + jl + nf * 16 + (lane & 15)] = f2bf(r);
                }
            }
        }
    }
    __syncthreads();

    // ---- Epilogue part 2: block-local prefix scan (f32), store prefixes + summary ----
    {
        const int j  = tid & 127;     // local j
        const int sg = tid >> 7;      // segment 0..3 (64 steps each)
        float A1 = 1.f, V1 = 0.f;
#pragma unroll 4
        for (int t = 0; t < 64; ++t) {
            const int s = sg * 64 + t;
            float a = bf2f(a_lds[s * 132 + j]);
            float g = bf2f(g_lds[s * 132 + j]);
            V1 = a * V1 + (1.f - a) * g;
            A1 *= a;
        }
        sumA[sg * 128 + j] = A1;
        sumV[sg * 128 + j] = V1;
        __syncthreads();
        float Ar = 1.f, Vr = 0.f;
        for (int k = 0; k < sg; ++k) {
            float Ak = sumA[k * 128 + j], Vk = sumV[k * 128 + j];
            Vr = Ak * Vr + Vk;
            Ar *= Ak;
        }
        ushort* ApG = Apref + (size_t)(m0 + sg * 64) * kH + j0 + j;
        ushort* VpG = Vpref + (size_t)(m0 + sg * 64) * kH + j0 + j;
#pragma unroll 4
        for (int t = 0; t < 64; ++t) {
            const int s = sg * 64 + t;
            float a = bf2f(a_lds[s * 132 + j]);
            float g = bf2f(g_lds[s * 132 + j]);
            Vr = a * Vr + (1.f - a) * g;
            Ar *= a;
            *ApG = f2bf(Ar);
            *VpG = f2bf(Vr);
            ApG += kH; VpG += kH;
        }
        if (sg == 3) {
            const int b = tm >> 3, c = tm & 7;      // chunk = 256 steps = this block
            cA[((b * 8 + c) << 10) + j0 + j] = Ar;  // f32 summary
            cV[((b * 8 + c) << 10) + j0 + j] = Vr;
        }
    }
}

// ---------------- mid-scan over 8 chunks/b; emits h_chunkstart + h_final ----------------
__global__ void scan_chunks_kernel(const float* __restrict__ cA, const float* __restrict__ cV,
                                   const float* __restrict__ h0, float* __restrict__ hstart,
                                   float* __restrict__ hfin)
{
    int idx = blockIdx.x * 256 + threadIdx.x;     // 8192 threads: (b, j)
    int j = idx & 1023, b = idx >> 10;
    float h = h0[(b << 10) + j];
    for (int c = 0; c < 8; ++c) {
        int o = ((b * 8 + c) << 10) + j;
        hstart[o] = h;
        h = cA[o] * h + cV[o];
    }
    hfin[(b << 10) + j] = h;
}

// ---------------- apply: elementwise out = A_pref*h_cs + V_pref + residual ----------------
template<bool WRITE_F32>
__global__ void apply_kernel(const ushort* __restrict__ Ap, const ushort* __restrict__ Vp,
                             const float* __restrict__ hst, const ushort* __restrict__ res,
                             void* __restrict__ outp)
{
    size_t i = ((size_t)blockIdx.x * 256 + threadIdx.x) * 4;
    int m = (int)(i >> 10);          // row
    int j = (int)(i & 1023);
    int b = m >> 11, s = m & 2047, c = s >> 8;
    f32x4 hcs = *reinterpret_cast<const f32x4*>(hst + (((b * 8 + c) << 10) + j));
    ushort4 Au = *reinterpret_cast<const ushort4*>(Ap + i);
    ushort4 Vu = *reinterpret_cast<const ushort4*>(Vp + i);
    ushort4 Ru = *reinterpret_cast<const ushort4*>(res + i);
    f32x4 o;
    o.x = bf2f(Au.x) * hcs.x + bf2f(Vu.x) + bf2f(Ru.x);
    o.y = bf2f(Au.y) * hcs.y + bf2f(Vu.y) + bf2f(Ru.y);
    o.z = bf2f(Au.z) * hcs.z + bf2f(Vu.z) + bf2f(Ru.z);
    o.w = bf2f(Au.w) * hcs.w + bf2f(Vu.w) + bf2f(Ru.w);
    if (WRITE_F32) {
        *reinterpret_cast<f32x4*>((float*)outp + i) = o;
    } else {
        ushort4 ob;
        ob.x = f2bf(o.x); ob.y = f2bf(o.y); ob.z = f2bf(o.z); ob.w = f2bf(o.w);
        *reinterpret_cast<ushort4*>((ushort*)outp + i) = ob;
    }
}

extern "C" void kernel_launch(void* const* d_in, const int* in_sizes, int n_in,
                              void* d_out, int out_size, void* d_ws, size_t ws_size,
                              hipStream_t stream)
{
    const float* x  = (const float*)d_in[0];
    const float* h  = (const float*)d_in[1];   // (2, 8, 1, 1024)
    const float* w0 = (const float*)d_in[2];
    const float* b0 = (const float*)d_in[3];
    const float* w1 = (const float*)d_in[4];
    const float* b1 = (const float*)d_in[5];
    float* out = (float*)d_out;
    char* ws = (char*)d_ws;

    if (ws_size < kWsNeed) return;

    ushort* xb   = (ushort*)(ws + kOffXb);   // aliases inpb (apply-L0 overwrites in place)
    ushort* inpb = (ushort*)(ws + kOffXb);
    ushort* w0b  = (ushort*)(ws + kOffW0);
    ushort* w1b  = (ushort*)(ws + kOffW1);
    ushort* Ap   = (ushort*)(ws + kOffA);
    ushort* Vp   = (ushort*)(ws + kOffG);
    float*  cA   = (float*)(ws + kOffCA);
    float*  cV   = (float*)(ws + kOffCV);
    float*  hst  = (float*)(ws + kOffHst);

    float* out_h = out + (size_t)kM * kH;    // h_final region in d_out

    cvt3_kernel<<<(QX + 2 * QW) / 256, 256, 0, stream>>>(x, w0, w1, xb, w0b, w1b);

    const int gemm_grid  = (kM / BM) * (kN2 / 256);  // 512
    const int apply_grid = kM * kH / 4 / 256;        // 16384

    // ---- layer 0 ----
    gemm_scan_kernel<<<gemm_grid, 512, 0, stream>>>(xb, w0b, b0, Ap, Vp, cA, cV);
    scan_chunks_kernel<<<32, 256, 0, stream>>>(cA, cV, h, hst, out_h);
    apply_kernel<false><<<apply_grid, 256, 0, stream>>>(Ap, Vp, hst, xb, inpb);

    // ---- layer 1 ----
    gemm_scan_kernel<<<gemm_grid, 512, 0, stream>>>(inpb, w1b, b1, Ap, Vp, cA, cV);
    scan_chunks_kernel<<<32, 256, 0, stream>>>(cA, cV, h + (size_t)kB * kH, hst, out_h + (size_t)kB * kH);
    apply_kernel<true><<<apply_grid, 256, 0, stream>>>(Ap, Vp, hst, inpb, out);
}

// Round 11
// 268.341 us; speedup vs baseline: 1.3259x; 1.0074x over previous
//
#include <hip/hip_runtime.h>
#include <hip/hip_bf16.h>
#include <cstdint>
#include <cstddef>

#define GAS __attribute__((address_space(1)))
#define LAS __attribute__((address_space(3)))

typedef __attribute__((ext_vector_type(8))) __bf16 bf16x8;
typedef __attribute__((ext_vector_type(4))) float f32x4;

constexpr int kB = 8, kS = 2048, kK = 1024, kH = 1024;
constexpr int kM = kB * kS;      // 16384 rows
constexpr int kN2 = 2 * kH;
constexpr int BM = 128, BK = 32;
constexpr int NKT = kK / BK;     // 32 K-tiles
constexpr int kChunks = 16;      // per batch, 128 steps each

// workspace layout (bytes)
constexpr size_t kOffXb   = 0;                    // bf16 x (33,554,432) -- later reused as inpb
constexpr size_t kOffW0   = 33554432;             // bf16 w0 (4,194,304)
constexpr size_t kOffW1   = 37748736;             // bf16 w1 (4,194,304)
constexpr size_t kOffA    = 41943040;             // bf16 A_pref (33,554,432)
constexpr size_t kOffG    = 75497472;             // bf16 V_pref (33,554,432)
constexpr size_t kOffCA   = 109051904;            // f32 chunk A (524,288)
constexpr size_t kOffCV   = 109576192;            // f32 chunk V (524,288)
constexpr size_t kOffHst  = 110100480;            // f32 chunk h-start (524,288)
constexpr size_t kWsNeed  = 115343360;

__device__ __forceinline__ ushort f2bf(float f) {
    union { float f; uint32_t u; } v; v.f = f;
    uint32_t r = v.u + 0x7FFFu + ((v.u >> 16) & 1u);
    return (ushort)(r >> 16);
}
__device__ __forceinline__ float bf2f(ushort u) {
    union { uint32_t u; float f; } v; v.u = (uint32_t)u << 16;
    return v.f;
}

// ---------------- fp32 -> bf16 convert: x, w0, w1 in ONE launch ----------------
constexpr int QX = kM * kK / 4;
constexpr int QW = kN2 * kK / 4;
__global__ void cvt3_kernel(const float* __restrict__ x, const float* __restrict__ w0,
                            const float* __restrict__ w1,
                            ushort* __restrict__ xb, ushort* __restrict__ w0b,
                            ushort* __restrict__ w1b)
{
    int i = blockIdx.x * 256 + threadIdx.x;
    const float* s; ushort* d;
    if (i < QX)            { s = x  + (size_t)i * 4;            d = xb  + (size_t)i * 4; }
    else if (i < QX + QW)  { int k = i - QX;      s = w0 + (size_t)k * 4; d = w0b + (size_t)k * 4; }
    else                   { int k = i - QX - QW; s = w1 + (size_t)k * 4; d = w1b + (size_t)k * 4; }
    f32x4 v = *reinterpret_cast<const f32x4*>(s);
    ushort4 o;
    o.x = f2bf(v.x); o.y = f2bf(v.y); o.z = f2bf(v.z); o.w = f2bf(v.w);
    *reinterpret_cast<ushort4*>(d) = o;
}

// ---------------- GEMM + gating + fused block-local scan: 2-blocks/CU variant ----------------
// Block = 256 threads (4 waves, 2m x 2n; per wave 64m x 128n, acc[4][8]).
// Tile: 128 m-rows (one 128-step chunk) x 128 j (gate W rows j0.. + hidden W rows 1024+j0..).
// K-loop: BK=32, 3-deep LDS ring (3 x 24 KB), counted vmcnt(6) (never 0 in main loop),
// 2 phases/tile {ds_read || stage-issue -> barrier -> lgkmcnt(0) -> setprio 16 MFMA -> barrier}.
// T2 XOR swizzle both-sides (r6-validated formulas, identities re-derived for this geometry).
// LDS 75.8 KB + launch_bounds(256,2) -> 2 independent blocks/CU (the round-11 lever).
__global__ __launch_bounds__(256, 2)
void gemm_scan_kernel(const ushort* __restrict__ A, const ushort* __restrict__ W,
                      const float* __restrict__ bias,
                      ushort* __restrict__ Apref, ushort* __restrict__ Vpref,
                      float* __restrict__ cA, float* __restrict__ cV)
{
    // ring: 3 bufs x { A 128x32 (8 KB) @0, B 256x32 (16 KB) @8192 } = 73728 B
    // overlay: a_lds [128][132] bf16 @0 (33792), g_lds @33792, sumA f32x4[8][32] @67584,
    // sumV @71680 -> total 75776 B
    __shared__ ushort smem[37888];

    const int tid  = threadIdx.x;
    const int lane = tid & 63;
    const int wv   = tid >> 6;     // 0..3
    const int wm   = wv >> 1;      // 0..1 : 64-row half
    const int wn   = wv & 1;       // 0..1 : gate / hidden half of B

    // XCD-bijective swizzle: 1024 blocks, 8 XCDs (each XCD: 16 tm x all 8 tn)
    const int bid = blockIdx.x;
    const int sid = (bid & 7) * 128 + (bid >> 3);
    const int tm  = sid >> 3;      // 0..127
    const int tn  = sid & 7;
    const int m0  = tm * BM;
    const int j0  = tn * 128;
    const int b   = tm >> 4;       // batch
    const int c   = tm & 15;       // chunk within batch

    f32x4 acc[4][8];
#pragma unroll
    for (int i = 0; i < 4; ++i)
#pragma unroll
        for (int j = 0; j < 8; ++j) acc[i][j] = (f32x4){0.f, 0.f, 0.f, 0.f};

    // staging: thread t -> row (t>>2) within a 64-row group, linear dest slot (t&3);
    // pre-swizzled source k-slot: sslot = (t&3) ^ ((srow>>1)&3) = (t&3) ^ ((t>>3)&3)
    const int srow  = tid >> 2;                    // 0..63
    const int sslot = (tid & 3) ^ ((tid >> 3) & 3);
    const int scol  = sslot * 8;
    const int tid16 = tid * 16;                    // bytes

    const ushort* ga0 = A + (size_t)(m0 + srow) * kK + scol;            // A rows 0..63 (+65536 elems = rows 64..127)
    const ushort* gb0 = W + (size_t)(j0 + srow) * kK + scol;            // gate rows
    const ushort* gb1 = W + (size_t)(1024 + j0 + srow) * kK + scol;     // hidden rows

    char* lds = (char*)smem;

    // read swizzle (r6-validated): slot = (lane>>4) ^ ((row>>1)&3) = (lane>>4) ^ ((lane>>1)&3)
    const int rslot = (lane >> 4) ^ ((lane >> 1) & 3);
    const int rb    = (lane & 15) * 64 + rslot * 16;
    const int aoff  = wm * 4096 + rb;              // within A block of a buf
    const int boff  = 8192 + wn * 8192 + rb;       // within buf (B base 8192)

#define VMWAIT(N) asm volatile("s_waitcnt vmcnt(" #N ")" ::: "memory")

#define STG3A(S) do {                                                            \
    __builtin_amdgcn_global_load_lds((const GAS void*)(ga0),                     \
        (LAS void*)(lds + (S) * 24576 + tid16),          16, 0, 0);              \
    __builtin_amdgcn_global_load_lds((const GAS void*)(ga0 + 65536),             \
        (LAS void*)(lds + (S) * 24576 + 4096 + tid16),   16, 0, 0);              \
    __builtin_amdgcn_global_load_lds((const GAS void*)(gb0),                     \
        (LAS void*)(lds + (S) * 24576 + 8192 + tid16),   16, 0, 0);              \
  } while (0)

#define STG3B(S) do {                                                            \
    __builtin_amdgcn_global_load_lds((const GAS void*)(gb0 + 65536),             \
        (LAS void*)(lds + (S) * 24576 + 12288 + tid16),  16, 0, 0);              \
    __builtin_amdgcn_global_load_lds((const GAS void*)(gb1),                     \
        (LAS void*)(lds + (S) * 24576 + 16384 + tid16),  16, 0, 0);              \
    __builtin_amdgcn_global_load_lds((const GAS void*)(gb1 + 65536),             \
        (LAS void*)(lds + (S) * 24576 + 20480 + tid16),  16, 0, 0);              \
    ga0 += BK; gb0 += BK; gb1 += BK;                                             \
  } while (0)

#define TILE_GEN(BUF, SA, SB, EW) do {                                           \
    bf16x8 af_[4], bf_[4];                                                       \
    _Pragma("unroll")                                                            \
    for (int mf_ = 0; mf_ < 4; ++mf_)                                            \
        af_[mf_] = *reinterpret_cast<const bf16x8*>(                             \
            lds + (BUF) * 24576 + aoff + mf_ * 1024);                            \
    _Pragma("unroll")                                                            \
    for (int nf_ = 0; nf_ < 4; ++nf_)                                            \
        bf_[nf_] = *reinterpret_cast<const bf16x8*>(                             \
            lds + (BUF) * 24576 + boff + nf_ * 1024);                            \
    SA;                                                                          \
    __builtin_amdgcn_s_barrier();                                                \
    asm volatile("s_waitcnt lgkmcnt(0)" ::: "memory");                           \
    __builtin_amdgcn_sched_barrier(0);                                           \
    __builtin_amdgcn_s_setprio(1);                                               \
    _Pragma("unroll")                                                            \
    for (int mf_ = 0; mf_ < 4; ++mf_)                                            \
        _Pragma("unroll")                                                        \
        for (int nf_ = 0; nf_ < 4; ++nf_)                                        \
            acc[mf_][nf_] = __builtin_amdgcn_mfma_f32_16x16x32_bf16(             \
                af_[mf_], bf_[nf_], acc[mf_][nf_], 0, 0, 0);                     \
    __builtin_amdgcn_s_setprio(0);                                               \
    __builtin_amdgcn_s_barrier();                                                \
    _Pragma("unroll")                                                            \
    for (int nf_ = 0; nf_ < 4; ++nf_)                                            \
        bf_[nf_] = *reinterpret_cast<const bf16x8*>(                             \
            lds + (BUF) * 24576 + boff + (4 + nf_) * 1024);                      \
    SB;                                                                          \
    __builtin_amdgcn_s_barrier();                                                \
    asm volatile("s_waitcnt lgkmcnt(0)" ::: "memory");                           \
    __builtin_amdgcn_sched_barrier(0);                                           \
    __builtin_amdgcn_s_setprio(1);                                               \
    _Pragma("unroll")                                                            \
    for (int mf_ = 0; mf_ < 4; ++mf_)                                            \
        _Pragma("unroll")                                                        \
        for (int nf_ = 0; nf_ < 4; ++nf_)                                        \
            acc[mf_][4 + nf_] = __builtin_amdgcn_mfma_f32_16x16x32_bf16(         \
                af_[mf_], bf_[nf_], acc[mf_][4 + nf_], 0, 0, 0);                 \
    __builtin_amdgcn_s_setprio(0);                                               \
    EW;                                                                          \
    __builtin_amdgcn_s_barrier();                                                \
  } while (0)

#define TILE(BUF, SBUF) TILE_GEN(BUF, STG3A(SBUF), STG3B(SBUF), VMWAIT(6))
#define TAIL0(BUF)      TILE_GEN(BUF, (void)0, (void)0, VMWAIT(0))
#define TAIL1(BUF)      TILE_GEN(BUF, (void)0, (void)0, (void)0)

    // prologue: stage tiles 0,1; retire tile 0 (vmcnt(6) leaves tile 1 in flight)
    STG3A(0); STG3B(0);
    STG3A(1); STG3B(1);
    VMWAIT(6);
    __builtin_amdgcn_s_barrier();

    for (int g = 0; g < 10; ++g) {
        TILE(0, 2);     // compute 3g,   stage 3g+2
        TILE(1, 0);     // compute 3g+1, stage 3g+3
        TILE(2, 1);     // compute 3g+2, stage 3g+4
    }
    TAIL0(0);           // tile 30 (vmcnt(0) retires tile 31)
    TAIL1(1);           // tile 31

#undef TILE
#undef TAIL0
#undef TAIL1
#undef TILE_GEN
#undef STG3A
#undef STG3B
#undef VMWAIT

    // ---- Epilogue part 1: gating transform -> LDS ----
    ushort* a_lds = smem;                      // [128][132] bf16
    ushort* g_lds = smem + 16896;              // ushort index (33792 B)
    f32x4*  sA4   = (f32x4*)(lds + 67584);     // [8][32]
    f32x4*  sV4   = (f32x4*)(lds + 71680);

    {
        const bool isG = (wn == 0);
        ushort* tgt = isG ? a_lds : g_lds;
        float bn[8];
#pragma unroll
        for (int nf = 0; nf < 8; ++nf)
            bn[nf] = bias[(isG ? 0 : 1024) + j0 + nf * 16 + (lane & 15)];
#pragma unroll
        for (int mf = 0; mf < 4; ++mf) {
#pragma unroll
            for (int i = 0; i < 4; ++i) {
                const int m = wm * 64 + mf * 16 + (lane >> 4) * 4 + i;  // 0..127 local s
#pragma unroll
                for (int nf = 0; nf < 8; ++nf) {
                    float val = acc[mf][nf][i] + bn[nf];
                    float r;
                    if (isG) r = 1.f / (1.f + __expf(val));                 // sigmoid(-gate)
                    else     r = (val >= 0.f) ? val + 0.5f : 1.f / (1.f + __expf(-val)); // g(hidden)
                    tgt[m * 132 + nf * 16 + (lane & 15)] = f2bf(r);
                }
            }
        }
    }
    __syncthreads();

    // ---- Epilogue part 2: f32 prefix scan over 128 steps, j-quads, ushort4 stores ----
    {
        const int jq = tid & 31;      // j-quad: j = jq*4
        const int sg = tid >> 5;      // segment 0..7 (16 steps each)
        f32x4 A1 = (f32x4){1.f, 1.f, 1.f, 1.f};
        f32x4 V1 = (f32x4){0.f, 0.f, 0.f, 0.f};
#pragma unroll 4
        for (int t = 0; t < 16; ++t) {
            const int s = sg * 16 + t;
            ushort4 au = *reinterpret_cast<const ushort4*>(a_lds + s * 132 + jq * 4);
            ushort4 gu = *reinterpret_cast<const ushort4*>(g_lds + s * 132 + jq * 4);
            f32x4 a = (f32x4){bf2f(au.x), bf2f(au.y), bf2f(au.z), bf2f(au.w)};
            f32x4 g = (f32x4){bf2f(gu.x), bf2f(gu.y), bf2f(gu.z), bf2f(gu.w)};
            V1 = a * V1 + (1.f - a) * g;
            A1 *= a;
        }
        sA4[sg * 32 + jq] = A1;
        sV4[sg * 32 + jq] = V1;
        __syncthreads();
        f32x4 Ar = (f32x4){1.f, 1.f, 1.f, 1.f};
        f32x4 Vr = (f32x4){0.f, 0.f, 0.f, 0.f};
        for (int k = 0; k < sg; ++k) {
            f32x4 Ak = sA4[k * 32 + jq], Vk = sV4[k * 32 + jq];
            Vr = Ak * Vr + Vk;
            Ar *= Ak;
        }
        ushort* ApG = Apref + (size_t)(m0 + sg * 16) * kH + j0 + jq * 4;
        ushort* VpG = Vpref + (size_t)(m0 + sg * 16) * kH + j0 + jq * 4;
#pragma unroll 4
        for (int t = 0; t < 16; ++t) {
            const int s = sg * 16 + t;
            ushort4 au = *reinterpret_cast<const ushort4*>(a_lds + s * 132 + jq * 4);
            ushort4 gu = *reinterpret_cast<const ushort4*>(g_lds + s * 132 + jq * 4);
            f32x4 a = (f32x4){bf2f(au.x), bf2f(au.y), bf2f(au.z), bf2f(au.w)};
            f32x4 g = (f32x4){bf2f(gu.x), bf2f(gu.y), bf2f(gu.z), bf2f(gu.w)};
            Vr = a * Vr + (1.f - a) * g;
            Ar *= a;
            ushort4 oa, ov;
            oa.x = f2bf(Ar.x); oa.y = f2bf(Ar.y); oa.z = f2bf(Ar.z); oa.w = f2bf(Ar.w);
            ov.x = f2bf(Vr.x); ov.y = f2bf(Vr.y); ov.z = f2bf(Vr.z); ov.w = f2bf(Vr.w);
            *reinterpret_cast<ushort4*>(ApG) = oa;
            *reinterpret_cast<ushort4*>(VpG) = ov;
            ApG += kH; VpG += kH;
        }
        if (sg == 7) {
            size_t o = ((size_t)(b * kChunks + c) << 10) + j0 + jq * 4;
            *reinterpret_cast<f32x4*>(cA + o) = Ar;
            *reinterpret_cast<f32x4*>(cV + o) = Vr;
        }
    }
}

// ---------------- mid-scan over 16 chunks/b; emits h_chunkstart + h_final ----------------
__global__ void scan_chunks_kernel(const float* __restrict__ cA, const float* __restrict__ cV,
                                   const float* __restrict__ h0, float* __restrict__ hstart,
                                   float* __restrict__ hfin)
{
    int idx = blockIdx.x * 256 + threadIdx.x;     // 8192 threads: (b, j)
    int j = idx & 1023, bb = idx >> 10;
    float h = h0[(bb << 10) + j];
    for (int c = 0; c < kChunks; ++c) {
        int o = ((bb * kChunks + c) << 10) + j;
        hstart[o] = h;
        h = cA[o] * h + cV[o];
    }
    hfin[(bb << 10) + j] = h;
}

// ---------------- apply: elementwise out = A_pref*h_cs + V_pref + residual ----------------
template<bool WRITE_F32>
__global__ void apply_kernel(const ushort* __restrict__ Ap, const ushort* __restrict__ Vp,
                             const float* __restrict__ hst, const ushort* __restrict__ res,
                             void* __restrict__ outp)
{
    size_t i = ((size_t)blockIdx.x * 256 + threadIdx.x) * 4;
    int m = (int)(i >> 10);          // row
    int j = (int)(i & 1023);
    int bb = m >> 11, s = m & 2047, c = s >> 7;
    f32x4 hcs = *reinterpret_cast<const f32x4*>(hst + (((bb * kChunks + c) << 10) + j));
    ushort4 Au = *reinterpret_cast<const ushort4*>(Ap + i);
    ushort4 Vu = *reinterpret_cast<const ushort4*>(Vp + i);
    ushort4 Ru = *reinterpret_cast<const ushort4*>(res + i);
    f32x4 o;
    o.x = bf2f(Au.x) * hcs.x + bf2f(Vu.x) + bf2f(Ru.x);
    o.y = bf2f(Au.y) * hcs.y + bf2f(Vu.y) + bf2f(Ru.y);
    o.z = bf2f(Au.z) * hcs.z + bf2f(Vu.z) + bf2f(Ru.z);
    o.w = bf2f(Au.w) * hcs.w + bf2f(Vu.w) + bf2f(Ru.w);
    if (WRITE_F32) {
        *reinterpret_cast<f32x4*>((float*)outp + i) = o;
    } else {
        ushort4 ob;
        ob.x = f2bf(o.x); ob.y = f2bf(o.y); ob.z = f2bf(o.z); ob.w = f2bf(o.w);
        *reinterpret_cast<ushort4*>((ushort*)outp + i) = ob;
    }
}

extern "C" void kernel_launch(void* const* d_in, const int* in_sizes, int n_in,
                              void* d_out, int out_size, void* d_ws, size_t ws_size,
                              hipStream_t stream)
{
    const float* x  = (const float*)d_in[0];
    const float* h  = (const float*)d_in[1];   // (2, 8, 1, 1024)
    const float* w0 = (const float*)d_in[2];
    const float* b0 = (const float*)d_in[3];
    const float* w1 = (const float*)d_in[4];
    const float* b1 = (const float*)d_in[5];
    float* out = (float*)d_out;
    char* ws = (char*)d_ws;

    if (ws_size < kWsNeed) return;

    ushort* xb   = (ushort*)(ws + kOffXb);   // aliases inpb (apply-L0 overwrites in place)
    ushort* inpb = (ushort*)(ws + kOffXb);
    ushort* w0b  = (ushort*)(ws + kOffW0);
    ushort* w1b  = (ushort*)(ws + kOffW1);
    ushort* Ap   = (ushort*)(ws + kOffA);
    ushort* Vp   = (ushort*)(ws + kOffG);
    float*  cA   = (float*)(ws + kOffCA);
    float*  cV   = (float*)(ws + kOffCV);
    float*  hst  = (float*)(ws + kOffHst);

    float* out_h = out + (size_t)kM * kH;    // h_final region in d_out

    cvt3_kernel<<<(QX + 2 * QW) / 256, 256, 0, stream>>>(x, w0, w1, xb, w0b, w1b);

    const int gemm_grid  = (kM / BM) * (kN2 / 256);  // 128 * 8 = 1024
    const int apply_grid = kM * kH / 4 / 256;        // 16384

    // ---- layer 0 ----
    gemm_scan_kernel<<<gemm_grid, 256, 0, stream>>>(xb, w0b, b0, Ap, Vp, cA, cV);
    scan_chunks_kernel<<<32, 256, 0, stream>>>(cA, cV, h, hst, out_h);
    apply_kernel<false><<<apply_grid, 256, 0, stream>>>(Ap, Vp, hst, xb, inpb);

    // ---- layer 1 ----
    gemm_scan_kernel<<<gemm_grid, 256, 0, stream>>>(inpb, w1b, b1, Ap, Vp, cA, cV);
    scan_chunks_kernel<<<32, 256, 0, stream>>>(cA, cV, h + (size_t)kB * kH, hst, out_h + (size_t)kB * kH);
    apply_kernel<true><<<apply_grid, 256, 0, stream>>>(Ap, Vp, hst, inpb, out);
}